// Round 3
// baseline (233.527 us; speedup 1.0000x reference)
//
#include <hip/hip_runtime.h>
#include <cstdint>

// Hierarchical classification head, R3 structure:
//   cast      : fp32->bf16 X, Wanc=[W1|W2|W3[0:280)], W3 full, biases; zero loss slot
//   gemm_anc  : AncZ = sigmoid(X @ Wanc^T + b)        [4096 x 640] bf16   (5.2 MB)
//   gemm_log  : z3 = sigmoid(X @ W3^T + b3); epilogue multiplies bf16 ancestors
//               from AncZ and writes logits3 DIRECTLY to d_out (no Z round-trip)
//   finalize  : per-row CE over out row + AncZ, atomicAdd mean loss
// GEMM K-loop: R1 single-buffer (measured better than R2 dbuf: 61 vs 64 us).

typedef unsigned short u16;
typedef __bf16 bf16;
typedef bf16 bf16x8 __attribute__((ext_vector_type(8)));
typedef float f32x4 __attribute__((ext_vector_type(4)));

#define AS_G __attribute__((address_space(1)))
#define AS_L __attribute__((address_space(3)))

constexpr int BATCH = 4096;
constexpr int H     = 1024;
constexpr int N1 = 28, N2 = 280, N3 = 2800;
constexpr int NA  = 588;    // ancestor cols: z1[28] z2[280] z3[0:280)
constexpr int NAP = 640;    // padded to 5*128
constexpr int N3P = 2816;   // padded to 22*128
constexpr int Z3OFF = N1 + N2;  // 308: offset of z3 block inside AncZ row

__device__ inline u16 f2bf(float f) {
    unsigned int u = __float_as_uint(f);
    u += 0x7fffu + ((u >> 16) & 1u);
    return (u16)(u >> 16);
}
__device__ inline float bf2f(unsigned int u) { return __uint_as_float(u << 16); }
__device__ inline float sigm(float v) { return 1.0f / (1.0f + __expf(-v)); }

// ---------------- cast ----------------
constexpr int XG  = (BATCH * H) / 4;  // 1,048,576
constexpr int WAG = (NAP * H) / 4;    //   163,840
constexpr int W3G = (N3P * H) / 4;    //   720,896
constexpr int BAG = NAP / 4;          //       160
constexpr int B3G = N3P / 4;          //       704
constexpr int CAST_TOT = XG + WAG + W3G + BAG + B3G;

__global__ __launch_bounds__(256) void cast_kernel(
        const float* __restrict__ x,
        const float* __restrict__ W1, const float* __restrict__ W2,
        const float* __restrict__ W3,
        const float* __restrict__ b1, const float* __restrict__ b2,
        const float* __restrict__ b3,
        u16* __restrict__ Xb, u16* __restrict__ Wanc, u16* __restrict__ W3b,
        float* __restrict__ bias_anc, float* __restrict__ bias3,
        float* __restrict__ loss_slot) {
    int g = blockIdx.x * 256 + threadIdx.x;
    if (g == 0) loss_slot[0] = 0.f;
    if (g < XG) {
        float4 v = ((const float4*)x)[g];
        ((ushort4*)Xb)[g] = make_ushort4(f2bf(v.x), f2bf(v.y), f2bf(v.z), f2bf(v.w));
    } else if (g < XG + WAG) {
        int wg = g - XG;
        int row = wg >> 8, cg = wg & 255;
        float4 v = make_float4(0.f, 0.f, 0.f, 0.f);
        if (row < N1)           v = ((const float4*)W1)[row * 256 + cg];
        else if (row < Z3OFF)   v = ((const float4*)W2)[(row - N1) * 256 + cg];
        else if (row < NA)      v = ((const float4*)W3)[(row - Z3OFF) * 256 + cg];
        ((ushort4*)Wanc)[wg] = make_ushort4(f2bf(v.x), f2bf(v.y), f2bf(v.z), f2bf(v.w));
    } else if (g < XG + WAG + W3G) {
        int wg = g - XG - WAG;
        int row = wg >> 8, cg = wg & 255;
        float4 v = make_float4(0.f, 0.f, 0.f, 0.f);
        if (row < N3) v = ((const float4*)W3)[row * 256 + cg];
        ((ushort4*)W3b)[wg] = make_ushort4(f2bf(v.x), f2bf(v.y), f2bf(v.z), f2bf(v.w));
    } else if (g < XG + WAG + W3G + BAG) {
        int bg = g - XG - WAG - W3G;
        float4 v; float* vp = &v.x;
        #pragma unroll
        for (int i = 0; i < 4; ++i) {
            int c = bg * 4 + i; float t = 0.f;
            if (c < N1)         t = b1[c];
            else if (c < Z3OFF) t = b2[c - N1];
            else if (c < NA)    t = b3[c - Z3OFF];
            vp[i] = t;
        }
        ((float4*)bias_anc)[bg] = v;
    } else if (g < CAST_TOT) {
        int bg = g - XG - WAG - W3G - BAG;
        float4 v; float* vp = &v.x;
        #pragma unroll
        for (int i = 0; i < 4; ++i) {
            int c = bg * 4 + i;
            vp[i] = (c < N3) ? b3[c] : 0.f;
        }
        ((float4*)bias3)[bg] = v;
    }
}

// ---------------- shared GEMM K-loop (single-buffer, 128x128, BK=32) ----------------
#define GEMM_PROLOG(Bmat)                                                                  \
    __shared__ __align__(16) u16 As[128 * 32];                                             \
    __shared__ __align__(16) u16 Bs[128 * 32];                                             \
    const int tid  = threadIdx.x;                                                          \
    const int lane = tid & 63;                                                             \
    const int wave = tid >> 6;                                                             \
    const int m0 = blockIdx.y * 128;                                                       \
    const int n0 = blockIdx.x * 128;                                                       \
    const int wr = wave >> 1;                                                              \
    const int wc = wave & 1;                                                               \
    const int c0 = tid, c1 = tid + 256;                                                    \
    const int r0 = c0 >> 2, o0 = (c0 & 3) * 8;                                             \
    const int r1 = c1 >> 2, o1 = (c1 & 3) * 8;                                             \
    const int laneM = lane & 15;                                                           \
    const int laneK = (lane >> 4) * 8;                                                     \
    f32x4 acc[4][4] = {};                                                                  \
    for (int kt = 0; kt < H / 32; ++kt) {                                                  \
        const int k0 = kt * 32;                                                            \
        __builtin_amdgcn_global_load_lds((const AS_G uint32_t*)(Xb + (size_t)(m0 + r0) * H + k0 + o0), \
                                         (AS_L uint32_t*)&As[c0 * 8], 16, 0, 0);           \
        __builtin_amdgcn_global_load_lds((const AS_G uint32_t*)(Xb + (size_t)(m0 + r1) * H + k0 + o1), \
                                         (AS_L uint32_t*)&As[c1 * 8], 16, 0, 0);           \
        __builtin_amdgcn_global_load_lds((const AS_G uint32_t*)(Bmat + (size_t)(n0 + r0) * H + k0 + o0), \
                                         (AS_L uint32_t*)&Bs[c0 * 8], 16, 0, 0);           \
        __builtin_amdgcn_global_load_lds((const AS_G uint32_t*)(Bmat + (size_t)(n0 + r1) * H + k0 + o1), \
                                         (AS_L uint32_t*)&Bs[c1 * 8], 16, 0, 0);           \
        __syncthreads();                                                                   \
        bf16x8 af[4], bfv[4];                                                              \
        _Pragma("unroll")                                                                  \
        for (int i = 0; i < 4; ++i) {                                                      \
            af[i]  = *(const bf16x8*)&As[(wr * 64 + i * 16 + laneM) * 32 + laneK];         \
            bfv[i] = *(const bf16x8*)&Bs[(wc * 64 + i * 16 + laneM) * 32 + laneK];         \
        }                                                                                  \
        _Pragma("unroll")                                                                  \
        for (int am = 0; am < 4; ++am)                                                     \
            _Pragma("unroll")                                                              \
            for (int bn = 0; bn < 4; ++bn)                                                 \
                acc[am][bn] = __builtin_amdgcn_mfma_f32_16x16x32_bf16(af[am], bfv[bn],     \
                                                                      acc[am][bn], 0, 0, 0); \
        __syncthreads();                                                                   \
    }

// ---------------- pass 1: AncZ = sigmoid(X @ Wanc^T + b), bf16 [4096 x 640] ----------------
__global__ __launch_bounds__(256) void gemm_anc(
        const u16* __restrict__ Xb, const u16* __restrict__ Wanc,
        const float* __restrict__ bias_anc, u16* __restrict__ AncZ) {
    GEMM_PROLOG(Wanc)
    #pragma unroll
    for (int bn = 0; bn < 4; ++bn) {
        const int col = n0 + wc * 64 + bn * 16 + laneM;    // < 640, pad cols stored too
        const float bias = bias_anc[col];
        #pragma unroll
        for (int am = 0; am < 4; ++am) {
            const int rbase = m0 + wr * 64 + am * 16 + (lane >> 4) * 4;
            #pragma unroll
            for (int r = 0; r < 4; ++r)
                AncZ[(size_t)(rbase + r) * NAP + col] = f2bf(sigm(acc[am][bn][r] + bias));
        }
    }
}

// ---------------- pass 2: logits3 = sigmoid(X@W3^T+b3) * anc2 * anc1 -> d_out ----------------
__global__ __launch_bounds__(256) void gemm_logits(
        const u16* __restrict__ Xb, const u16* __restrict__ W3b,
        const float* __restrict__ bias3, const u16* __restrict__ AncZ,
        float* __restrict__ out) {
    GEMM_PROLOG(W3b)
    #pragma unroll
    for (int bn = 0; bn < 4; ++bn) {
        const int col = n0 + wc * 64 + bn * 16 + laneM;
        if (col >= N3) continue;                 // pad columns of last tile
        const float bias = bias3[col];
        const int a1 = Z3OFF + col / 100;        // z3[col/100] slot in AncZ row
        const int a2 = Z3OFF + col / 10;         // z3[col/10]
        #pragma unroll
        for (int am = 0; am < 4; ++am) {
            const int rbase = m0 + wr * 64 + am * 16 + (lane >> 4) * 4;
            #pragma unroll
            for (int r = 0; r < 4; ++r) {
                const size_t row = rbase + r;
                const float z3  = sigm(acc[am][bn][r] + bias);
                const float anc1 = bf2f(AncZ[row * NAP + a1]);
                const float anc2 = bf2f(AncZ[row * NAP + a2]);
                out[row * N3 + col] = z3 * anc2 * anc1;
            }
        }
    }
}

// ---------------- finalize: per-row CE, atomic mean loss ----------------
__global__ __launch_bounds__(256) void finalize(
        const float* __restrict__ out, const u16* __restrict__ AncZ,
        const int* __restrict__ labels, float* __restrict__ loss_slot) {
    __shared__ float zs[NAP];
    __shared__ float red[12];
    const int b = blockIdx.x, tid = threadIdx.x;

    const unsigned int* Ar = (const unsigned int*)(AncZ + (size_t)b * NAP);
    for (int i = tid; i < NAP / 2; i += 256) {
        unsigned int v = Ar[i];
        zs[2 * i]     = bf2f(v & 0xffffu);
        zs[2 * i + 1] = bf2f(v >> 16);
    }
    __syncthreads();
    const float* z1s = zs;
    const float* z2s = zs + N1;

    const float* outr = out + (size_t)b * N3;
    float se1 = 0.f, se2 = 0.f, se3 = 0.f;
    for (int k = tid; k < N3; k += 256)
        se3 += __expf(outr[k]);
    for (int j = tid; j < N2; j += 256)
        se2 += __expf(z2s[j] * z2s[j / 10]);
    if (tid < N1)
        se1 = __expf(z1s[tid]);

    #pragma unroll
    for (int off = 32; off > 0; off >>= 1) {
        se1 += __shfl_down(se1, off, 64);
        se2 += __shfl_down(se2, off, 64);
        se3 += __shfl_down(se3, off, 64);
    }
    if ((tid & 63) == 0) {
        int w = tid >> 6;
        red[w] = se3; red[4 + w] = se2; red[8 + w] = se1;
    }
    __syncthreads();
    if (tid == 0) {
        float s3 = red[0] + red[1] + red[2] + red[3];
        float s2 = red[4] + red[5] + red[6] + red[7];
        float s1 = red[8] + red[9] + red[10] + red[11];
        int lab  = labels[b];
        int lab2 = lab / 10, lab1 = lab / 100;
        float l1 = z1s[lab1];
        float l2 = z2s[lab2 / 10] * z2s[lab2];
        float l3 = outr[lab];
        float loss = (logf(s1) - l1) + (logf(s2) - l2) + (logf(s3) - l3);
        atomicAdd(loss_slot, loss * (1.0f / BATCH));
    }
}

extern "C" void kernel_launch(void* const* d_in, const int* in_sizes, int n_in,
                              void* d_out, int out_size, void* d_ws, size_t ws_size,
                              hipStream_t stream) {
    const float* x      = (const float*)d_in[0];
    const int*   labels = (const int*)d_in[1];
    const float* W1     = (const float*)d_in[2];
    const float* b1     = (const float*)d_in[3];
    const float* W2     = (const float*)d_in[4];
    const float* b2     = (const float*)d_in[5];
    const float* W3     = (const float*)d_in[6];
    const float* b3     = (const float*)d_in[7];
    float* out = (float*)d_out;
    float* loss_slot = out + (size_t)BATCH * N3;

    char* ws = (char*)d_ws;
    u16*   Xb       = (u16*)ws;                    //  8,388,608 B  [4096][1024]
    u16*   Wanc     = (u16*)(ws + 8388608);        //  1,310,720 B  [640][1024]
    u16*   W3b      = (u16*)(ws + 9699328);        //  5,767,168 B  [2816][1024]
    u16*   AncZ     = (u16*)(ws + 15466496);       //  5,242,880 B  [4096][640]
    float* bias_anc = (float*)(ws + 20709376);     //      2,560 B
    float* bias3    = (float*)(ws + 20711936);     //     11,264 B
    // total ws use: 20,723,200 B

    cast_kernel<<<(CAST_TOT + 255) / 256, 256, 0, stream>>>(
        x, W1, W2, W3, b1, b2, b3, Xb, Wanc, W3b, bias_anc, bias3, loss_slot);
    gemm_anc<<<dim3(NAP / 128, BATCH / 128), 256, 0, stream>>>(Xb, Wanc, bias_anc, AncZ);
    gemm_logits<<<dim3(N3P / 128, BATCH / 128), 256, 0, stream>>>(Xb, W3b, bias3, AncZ, out);
    finalize<<<BATCH, 256, 0, stream>>>(out, AncZ, labels, loss_slot);
}

// Round 4
// 205.273 us; speedup vs baseline: 1.1376x; 1.1376x over previous
//
#include <hip/hip_runtime.h>
#include <cstdint>

// Hierarchical classification head, R4 structure (back to R1 3-kernel shape):
//   cast        : fp32->bf16 X, W=[W1|W2|W3] (NP=3200 pad), bias; zero loss slot
//   gemm_sig    : Zb = sigmoid(X @ W^T + b) bf16 [4096 x 3200]
//                 + XCD-aware block swizzle: XCD = id%8 owns m-tiles [4x,4x+4),
//                 sweeps n with 4-m inner => per-XCD L2 working set ~3 MB.
//   logits_loss : per-row logits3 -> d_out (float4 writes), CE partials,
//                 atomicAdd mean loss (no 4th dispatch).

typedef unsigned short u16;
typedef __bf16 bf16;
typedef bf16 bf16x8 __attribute__((ext_vector_type(8)));
typedef float f32x4 __attribute__((ext_vector_type(4)));

#define AS_G __attribute__((address_space(1)))
#define AS_L __attribute__((address_space(3)))

constexpr int BATCH = 4096;
constexpr int H     = 1024;
constexpr int N1 = 28, N2 = 280, N3 = 2800;
constexpr int NT = N1 + N2 + N3;   // 3108 real output columns
constexpr int NP = 3200;           // padded to 25 * 128

__device__ inline u16 f2bf(float f) {
    unsigned int u = __float_as_uint(f);
    u += 0x7fffu + ((u >> 16) & 1u);
    return (u16)(u >> 16);
}
__device__ inline float bf2f(unsigned int u) { return __uint_as_float(u << 16); }

// ---------------- cast fp32 -> bf16 (RNE) + fused bias + loss-slot zero ----------------
constexpr int XG = (BATCH * H) / 4;   // 1,048,576 float4 groups of x
constexpr int WG = (NP * H) / 4;      //   819,200 groups of W (padded)
constexpr int BG = NP / 4;            //       800 groups of bias

__global__ __launch_bounds__(256) void cast_kernel(
        const float* __restrict__ x,
        const float* __restrict__ W1, const float* __restrict__ W2,
        const float* __restrict__ W3,
        const float* __restrict__ b1, const float* __restrict__ b2,
        const float* __restrict__ b3,
        u16* __restrict__ Xb, u16* __restrict__ Wb, float* __restrict__ biasf,
        float* __restrict__ loss_slot) {
    int g = blockIdx.x * 256 + threadIdx.x;
    if (g == 0) loss_slot[0] = 0.f;
    if (g < XG) {
        float4 v = ((const float4*)x)[g];
        ((ushort4*)Xb)[g] = make_ushort4(f2bf(v.x), f2bf(v.y), f2bf(v.z), f2bf(v.w));
    } else if (g < XG + WG) {
        int wg = g - XG;
        int row = wg >> 8, cg = wg & 255;
        float4 v = make_float4(0.f, 0.f, 0.f, 0.f);
        if (row < N1)           v = ((const float4*)W1)[row * 256 + cg];
        else if (row < N1 + N2) v = ((const float4*)W2)[(row - N1) * 256 + cg];
        else if (row < NT)      v = ((const float4*)W3)[(row - N1 - N2) * 256 + cg];
        ((ushort4*)Wb)[wg] = make_ushort4(f2bf(v.x), f2bf(v.y), f2bf(v.z), f2bf(v.w));
    } else if (g < XG + WG + BG) {
        int bg = g - XG - WG;
        float4 v; float* vp = &v.x;
        #pragma unroll
        for (int i = 0; i < 4; ++i) {
            int c = bg * 4 + i; float t = 0.f;
            if (c < N1)           t = b1[c];
            else if (c < N1 + N2) t = b2[c - N1];
            else if (c < NT)      t = b3[c - N1 - N2];
            vp[i] = t;
        }
        ((float4*)biasf)[bg] = v;
    }
}

// ---------------- GEMM: Zb = sigmoid(Xb @ Wb^T + bias), bf16 out ----------------
// Single-buffer K-loop (measured best), 128x128 tile, BK=32, 4 waves 2x2.
// Flat grid of 800 blocks; XCD-band swizzle for L2 residency.
__global__ __launch_bounds__(256) void gemm_sig(
        const u16* __restrict__ Xb, const u16* __restrict__ Wb,
        const float* __restrict__ biasf, u16* __restrict__ Zb) {
    __shared__ __align__(16) u16 As[128 * 32];
    __shared__ __align__(16) u16 Bs[128 * 32];

    // swizzle: id%8 = XCD (HW round-robin heuristic). XCD x owns m-tiles
    // [4x, 4x+4); j=id/8 sweeps n-major with 4-m inner. Working set per XCD:
    // 4 A-tiles (1 MB, resident all kernel) + ~8 B-tiles window (2 MB) < 4 MB L2.
    const int id  = blockIdx.x;        // 0..799
    const int xcd = id & 7;
    const int j   = id >> 3;           // 0..99
    const int m0 = ((xcd << 2) | (j & 3)) * 128;   // m-tile 0..31
    const int n0 = (j >> 2) * 128;                 // n-tile 0..24

    const int tid  = threadIdx.x;
    const int lane = tid & 63;
    const int wave = tid >> 6;
    const int wr = wave >> 1;
    const int wc = wave & 1;

    const int c0 = tid, c1 = tid + 256;
    const int r0 = c0 >> 2, o0 = (c0 & 3) * 8;
    const int r1 = c1 >> 2, o1 = (c1 & 3) * 8;

    const int laneM = lane & 15;
    const int laneK = (lane >> 4) * 8;

    f32x4 acc[4][4] = {};

    for (int kt = 0; kt < H / 32; ++kt) {
        const int k0 = kt * 32;
        __builtin_amdgcn_global_load_lds((const AS_G uint32_t*)(Xb + (size_t)(m0 + r0) * H + k0 + o0),
                                         (AS_L uint32_t*)&As[c0 * 8], 16, 0, 0);
        __builtin_amdgcn_global_load_lds((const AS_G uint32_t*)(Xb + (size_t)(m0 + r1) * H + k0 + o1),
                                         (AS_L uint32_t*)&As[c1 * 8], 16, 0, 0);
        __builtin_amdgcn_global_load_lds((const AS_G uint32_t*)(Wb + (size_t)(n0 + r0) * H + k0 + o0),
                                         (AS_L uint32_t*)&Bs[c0 * 8], 16, 0, 0);
        __builtin_amdgcn_global_load_lds((const AS_G uint32_t*)(Wb + (size_t)(n0 + r1) * H + k0 + o1),
                                         (AS_L uint32_t*)&Bs[c1 * 8], 16, 0, 0);
        __syncthreads();

        bf16x8 af[4], bfv[4];
        #pragma unroll
        for (int i = 0; i < 4; ++i) {
            af[i]  = *(const bf16x8*)&As[(wr * 64 + i * 16 + laneM) * 32 + laneK];
            bfv[i] = *(const bf16x8*)&Bs[(wc * 64 + i * 16 + laneM) * 32 + laneK];
        }
        #pragma unroll
        for (int am = 0; am < 4; ++am)
            #pragma unroll
            for (int bn = 0; bn < 4; ++bn)
                acc[am][bn] = __builtin_amdgcn_mfma_f32_16x16x32_bf16(af[am], bfv[bn], acc[am][bn], 0, 0, 0);
        __syncthreads();
    }

    // epilogue: C/D layout col = lane&15, row = (lane>>4)*4 + r; bf16 store
    #pragma unroll
    for (int bn = 0; bn < 4; ++bn) {
        const int col = n0 + wc * 64 + bn * 16 + laneM;
        if (col >= NT) continue;               // skip pad columns
        const float bias = biasf[col];
        #pragma unroll
        for (int am = 0; am < 4; ++am) {
            const int rbase = m0 + wr * 64 + am * 16 + (lane >> 4) * 4;
            #pragma unroll
            for (int r = 0; r < 4; ++r) {
                float v = acc[am][bn][r] + bias;
                Zb[(size_t)(rbase + r) * NP + col] = f2bf(1.0f / (1.0f + __expf(-v)));
            }
        }
    }
}

// ---------------- per-row logits + CE, atomic loss ----------------
__global__ __launch_bounds__(256) void logits_loss(
        const u16* __restrict__ Zb, const int* __restrict__ labels,
        float* __restrict__ out, float* __restrict__ loss_slot) {
    __shared__ float zs[NT];               // [0,28) z1 | [28,308) z2 | [308,3108) z3
    __shared__ float red[12];
    const int b = blockIdx.x, tid = threadIdx.x;

    // vectorized bf16 row load: NT=3108 u16 = 1554 uints
    const unsigned int* Zr = (const unsigned int*)(Zb + (size_t)b * NP);
    for (int i = tid; i < NT / 2; i += 256) {
        unsigned int v = Zr[i];
        zs[2 * i]     = bf2f(v & 0xffffu);
        zs[2 * i + 1] = bf2f(v >> 16);
    }
    __syncthreads();

    const float* z1s = zs;
    const float* z2s = zs + N1;
    const float* z3s = zs + N1 + N2;

    float se1 = 0.f, se2 = 0.f, se3 = 0.f;
    float4* outr4 = (float4*)(out + (size_t)b * N3);   // 11200 B row, 16B aligned
    // 700 float4 quads cover N3=2800
    for (int q = tid; q < N3 / 4; q += 256) {
        const int k = q * 4;
        float4 o;
        float* op = &o.x;
        #pragma unroll
        for (int u = 0; u < 4; ++u) {
            const int kk = k + u;
            float lg = z3s[kk] * z3s[kk / 10] * z3s[kk / 100];
            op[u] = lg;
            se3 += __expf(lg);
        }
        outr4[q] = o;
    }
    for (int jj = tid; jj < N2; jj += 256)
        se2 += __expf(z2s[jj] * z2s[jj / 10]);
    if (tid < N1)
        se1 = __expf(z1s[tid]);

    #pragma unroll
    for (int off = 32; off > 0; off >>= 1) {
        se1 += __shfl_down(se1, off, 64);
        se2 += __shfl_down(se2, off, 64);
        se3 += __shfl_down(se3, off, 64);
    }
    if ((tid & 63) == 0) {
        int w = tid >> 6;
        red[w] = se3; red[4 + w] = se2; red[8 + w] = se1;
    }
    __syncthreads();
    if (tid == 0) {
        float s3 = red[0] + red[1] + red[2] + red[3];
        float s2 = red[4] + red[5] + red[6] + red[7];
        float s1 = red[8] + red[9] + red[10] + red[11];
        int lab  = labels[b];
        int lab2 = lab / 10, lab1 = lab / 100;
        float l1 = z1s[lab1];
        float l2 = z2s[lab2] * z2s[lab2 / 10];
        float l3 = z3s[lab] * z3s[lab2] * z3s[lab1];
        float loss = (logf(s1) - l1) + (logf(s2) - l2) + (logf(s3) - l3);
        atomicAdd(loss_slot, loss * (1.0f / BATCH));
    }
}

extern "C" void kernel_launch(void* const* d_in, const int* in_sizes, int n_in,
                              void* d_out, int out_size, void* d_ws, size_t ws_size,
                              hipStream_t stream) {
    const float* x      = (const float*)d_in[0];
    const int*   labels = (const int*)d_in[1];
    const float* W1     = (const float*)d_in[2];
    const float* b1     = (const float*)d_in[3];
    const float* W2     = (const float*)d_in[4];
    const float* b2     = (const float*)d_in[5];
    const float* W3     = (const float*)d_in[6];
    const float* b3     = (const float*)d_in[7];
    float* out = (float*)d_out;
    float* loss_slot = out + (size_t)BATCH * N3;

    char* ws = (char*)d_ws;
    u16*   Xb    = (u16*)ws;                    //  8,388,608 B  [4096][1024]
    u16*   Wb    = (u16*)(ws + 8388608);        //  6,553,600 B  [3200][1024]
    u16*   Zb    = (u16*)(ws + 14942208);       // 26,214,400 B  [4096][3200]
    float* biasf = (float*)(ws + 41156608);     //     12,800 B  [3200]
    // total ws use: 41,169,408 B

    cast_kernel<<<(XG + WG + BG + 255) / 256, 256, 0, stream>>>(
        x, W1, W2, W3, b1, b2, b3, Xb, Wb, biasf, loss_slot);
    gemm_sig<<<800, 256, 0, stream>>>(Xb, Wb, biasf, Zb);
    logits_loss<<<BATCH, 256, 0, stream>>>(Zb, labels, out, loss_slot);
}

// Round 5
// 166.109 us; speedup vs baseline: 1.4059x; 1.2358x over previous
//
#include <hip/hip_runtime.h>
#include <cstdint>

// Hierarchical classification head, R5:
//   cast         : fp32->bf16 X, W=[W1|W2|W3] (NP=3200), bias
//   gemm_sig     : Zb = sigmoid(X @ W^T + b) bf16; BK=64 K-loop (16 barriers
//                  instead of 32; two 32-wide LDS panels keep the bank layout
//                  and the lane-contiguous global_load_lds constraint);
//                  XCD band swizzle kept (FETCH 85->34 MB measured in R4).
//   logits_loss  : per-row logits3 -> d_out (float4), CE partial per row
//                  (NO single-address atomic: measured +35-40 us in R2/R4)
//   final_reduce : 4096 partials -> mean loss scalar

typedef unsigned short u16;
typedef __bf16 bf16;
typedef bf16 bf16x8 __attribute__((ext_vector_type(8)));
typedef float f32x4 __attribute__((ext_vector_type(4)));

#define AS_G __attribute__((address_space(1)))
#define AS_L __attribute__((address_space(3)))

constexpr int BATCH = 4096;
constexpr int H     = 1024;
constexpr int N1 = 28, N2 = 280, N3 = 2800;
constexpr int NT = N1 + N2 + N3;   // 3108
constexpr int NP = 3200;           // 25 * 128

__device__ inline u16 f2bf(float f) {
    unsigned int u = __float_as_uint(f);
    u += 0x7fffu + ((u >> 16) & 1u);
    return (u16)(u >> 16);
}
__device__ inline float bf2f(unsigned int u) { return __uint_as_float(u << 16); }

// ---------------- cast fp32 -> bf16 (RNE) + fused bias ----------------
constexpr int XG = (BATCH * H) / 4;   // 1,048,576
constexpr int WG = (NP * H) / 4;      //   819,200
constexpr int BG = NP / 4;            //       800

__global__ __launch_bounds__(256) void cast_kernel(
        const float* __restrict__ x,
        const float* __restrict__ W1, const float* __restrict__ W2,
        const float* __restrict__ W3,
        const float* __restrict__ b1, const float* __restrict__ b2,
        const float* __restrict__ b3,
        u16* __restrict__ Xb, u16* __restrict__ Wb, float* __restrict__ biasf) {
    int g = blockIdx.x * 256 + threadIdx.x;
    if (g < XG) {
        float4 v = ((const float4*)x)[g];
        ((ushort4*)Xb)[g] = make_ushort4(f2bf(v.x), f2bf(v.y), f2bf(v.z), f2bf(v.w));
    } else if (g < XG + WG) {
        int wg = g - XG;
        int row = wg >> 8, cg = wg & 255;
        float4 v = make_float4(0.f, 0.f, 0.f, 0.f);
        if (row < N1)           v = ((const float4*)W1)[row * 256 + cg];
        else if (row < N1 + N2) v = ((const float4*)W2)[(row - N1) * 256 + cg];
        else if (row < NT)      v = ((const float4*)W3)[(row - N1 - N2) * 256 + cg];
        ((ushort4*)Wb)[wg] = make_ushort4(f2bf(v.x), f2bf(v.y), f2bf(v.z), f2bf(v.w));
    } else if (g < XG + WG + BG) {
        int bg = g - XG - WG;
        float4 v; float* vp = &v.x;
        #pragma unroll
        for (int i = 0; i < 4; ++i) {
            int c = bg * 4 + i; float t = 0.f;
            if (c < N1)           t = b1[c];
            else if (c < N1 + N2) t = b2[c - N1];
            else if (c < NT)      t = b3[c - N1 - N2];
            vp[i] = t;
        }
        ((float4*)biasf)[bg] = v;
    }
}

// ---------------- GEMM: Zb = sigmoid(Xb @ Wb^T + bias), bf16 out ----------------
// 128x128 tile, BK=64 as two 32-wide panels, 4 waves 2x2, 16 barrier-iters.
__global__ __launch_bounds__(256) void gemm_sig(
        const u16* __restrict__ Xb, const u16* __restrict__ Wb,
        const float* __restrict__ biasf, u16* __restrict__ Zb) {
    // [2 k-halves][128 rows][32 cols] per matrix
    __shared__ __align__(16) u16 As[2 * 128 * 32];
    __shared__ __align__(16) u16 Bs[2 * 128 * 32];

    // XCD band swizzle (R4: FETCH 85->34 MB)
    const int id  = blockIdx.x;        // 0..799
    const int xcd = id & 7;
    const int j   = id >> 3;           // 0..99
    const int m0 = ((xcd << 2) | (j & 3)) * 128;   // m-tile 0..31
    const int n0 = (j >> 2) * 128;                 // n-tile 0..24

    const int tid  = threadIdx.x;
    const int lane = tid & 63;
    const int wave = tid >> 6;
    const int wr = wave >> 1;
    const int wc = wave & 1;

    const int laneM = lane & 15;
    const int laneK = (lane >> 4) * 8;

    // staging: 1024 chunks of 16B per matrix per iter; thread does chunks
    // tid+256t, t=0..3. chunk c: h=c>>9, row=(c&511)>>2, o=(c&3)*8 elems.
    // LDS elem offset = 8*c (linear -> lane-contiguous), global = row*H + h*32 + o.
    int crow[4], cgoff[4];
    #pragma unroll
    for (int t = 0; t < 4; ++t) {
        const int c = tid + 256 * t;
        const int h = c >> 9, rem = c & 511;
        crow[t]  = rem >> 2;
        cgoff[t] = h * 32 + (rem & 3) * 8;
    }

    f32x4 acc[4][4] = {};

    for (int kt = 0; kt < H / 64; ++kt) {
        const int k0 = kt * 64;
        #pragma unroll
        for (int t = 0; t < 4; ++t) {
            const int c = tid + 256 * t;
            __builtin_amdgcn_global_load_lds(
                (const AS_G uint32_t*)(Xb + (size_t)(m0 + crow[t]) * H + k0 + cgoff[t]),
                (AS_L uint32_t*)&As[c * 8], 16, 0, 0);
            __builtin_amdgcn_global_load_lds(
                (const AS_G uint32_t*)(Wb + (size_t)(n0 + crow[t]) * H + k0 + cgoff[t]),
                (AS_L uint32_t*)&Bs[c * 8], 16, 0, 0);
        }
        __syncthreads();

        #pragma unroll
        for (int h = 0; h < 2; ++h) {
            bf16x8 af[4], bfv[4];
            #pragma unroll
            for (int i = 0; i < 4; ++i) {
                af[i]  = *(const bf16x8*)&As[h * 4096 + (wr * 64 + i * 16 + laneM) * 32 + laneK];
                bfv[i] = *(const bf16x8*)&Bs[h * 4096 + (wc * 64 + i * 16 + laneM) * 32 + laneK];
            }
            #pragma unroll
            for (int am = 0; am < 4; ++am)
                #pragma unroll
                for (int bn = 0; bn < 4; ++bn)
                    acc[am][bn] = __builtin_amdgcn_mfma_f32_16x16x32_bf16(af[am], bfv[bn], acc[am][bn], 0, 0, 0);
        }
        __syncthreads();
    }

    // epilogue: C/D layout col = lane&15, row = (lane>>4)*4 + r; bf16 store
    #pragma unroll
    for (int bn = 0; bn < 4; ++bn) {
        const int col = n0 + wc * 64 + bn * 16 + laneM;
        if (col >= NT) continue;
        const float bias = biasf[col];
        #pragma unroll
        for (int am = 0; am < 4; ++am) {
            const int rbase = m0 + wr * 64 + am * 16 + (lane >> 4) * 4;
            #pragma unroll
            for (int r = 0; r < 4; ++r) {
                float v = acc[am][bn][r] + bias;
                Zb[(size_t)(rbase + r) * NP + col] = f2bf(1.0f / (1.0f + __expf(-v)));
            }
        }
    }
}

// ---------------- per-row logits + CE partial (no atomic) ----------------
__global__ __launch_bounds__(256) void logits_loss(
        const u16* __restrict__ Zb, const int* __restrict__ labels,
        float* __restrict__ out, float* __restrict__ partials) {
    __shared__ float zs[NT];               // z1 | z2 | z3
    __shared__ float red[12];
    const int b = blockIdx.x, tid = threadIdx.x;

    const unsigned int* Zr = (const unsigned int*)(Zb + (size_t)b * NP);
    for (int i = tid; i < NT / 2; i += 256) {
        unsigned int v = Zr[i];
        zs[2 * i]     = bf2f(v & 0xffffu);
        zs[2 * i + 1] = bf2f(v >> 16);
    }
    __syncthreads();

    const float* z1s = zs;
    const float* z2s = zs + N1;
    const float* z3s = zs + N1 + N2;

    float se1 = 0.f, se2 = 0.f, se3 = 0.f;
    float4* outr4 = (float4*)(out + (size_t)b * N3);
    for (int q = tid; q < N3 / 4; q += 256) {
        const int k = q * 4;
        float4 o; float* op = &o.x;
        #pragma unroll
        for (int u = 0; u < 4; ++u) {
            const int kk = k + u;
            float lg = z3s[kk] * z3s[kk / 10] * z3s[kk / 100];
            op[u] = lg;
            se3 += __expf(lg);
        }
        outr4[q] = o;
    }
    for (int jj = tid; jj < N2; jj += 256)
        se2 += __expf(z2s[jj] * z2s[jj / 10]);
    if (tid < N1)
        se1 = __expf(z1s[tid]);

    #pragma unroll
    for (int off = 32; off > 0; off >>= 1) {
        se1 += __shfl_down(se1, off, 64);
        se2 += __shfl_down(se2, off, 64);
        se3 += __shfl_down(se3, off, 64);
    }
    if ((tid & 63) == 0) {
        int w = tid >> 6;
        red[w] = se3; red[4 + w] = se2; red[8 + w] = se1;
    }
    __syncthreads();
    if (tid == 0) {
        float s3 = red[0] + red[1] + red[2] + red[3];
        float s2 = red[4] + red[5] + red[6] + red[7];
        float s1 = red[8] + red[9] + red[10] + red[11];
        int lab  = labels[b];
        int lab2 = lab / 10, lab1 = lab / 100;
        float l1 = z1s[lab1];
        float l2 = z2s[lab2] * z2s[lab2 / 10];
        float l3 = z3s[lab] * z3s[lab2] * z3s[lab1];
        partials[b] = (logf(s1) - l1) + (logf(s2) - l2) + (logf(s3) - l3);
    }
}

// ---------------- final loss reduce ----------------
__global__ __launch_bounds__(256) void final_reduce(
        const float* __restrict__ partials, float* __restrict__ out) {
    __shared__ float red[4];
    const int tid = threadIdx.x;
    float s = 0.f;
    for (int i = tid; i < BATCH; i += 256) s += partials[i];
    #pragma unroll
    for (int off = 32; off > 0; off >>= 1) s += __shfl_down(s, off, 64);
    if ((tid & 63) == 0) red[tid >> 6] = s;
    __syncthreads();
    if (tid == 0)
        out[(size_t)BATCH * N3] = (red[0] + red[1] + red[2] + red[3]) * (1.0f / BATCH);
}

extern "C" void kernel_launch(void* const* d_in, const int* in_sizes, int n_in,
                              void* d_out, int out_size, void* d_ws, size_t ws_size,
                              hipStream_t stream) {
    const float* x      = (const float*)d_in[0];
    const int*   labels = (const int*)d_in[1];
    const float* W1     = (const float*)d_in[2];
    const float* b1     = (const float*)d_in[3];
    const float* W2     = (const float*)d_in[4];
    const float* b2     = (const float*)d_in[5];
    const float* W3     = (const float*)d_in[6];
    const float* b3     = (const float*)d_in[7];
    float* out = (float*)d_out;

    char* ws = (char*)d_ws;
    u16*   Xb       = (u16*)ws;                    //  8,388,608 B
    u16*   Wb       = (u16*)(ws + 8388608);        //  6,553,600 B
    u16*   Zb       = (u16*)(ws + 14942208);       // 26,214,400 B
    float* biasf    = (float*)(ws + 41156608);     //     12,800 B
    float* partials = (float*)(ws + 41169408);     //     16,384 B
    // total ws use: 41,185,792 B

    cast_kernel<<<(XG + WG + BG + 255) / 256, 256, 0, stream>>>(
        x, W1, W2, W3, b1, b2, b3, Xb, Wb, biasf);
    gemm_sig<<<800, 256, 0, stream>>>(Xb, Wb, biasf, Zb);
    logits_loss<<<BATCH, 256, 0, stream>>>(Zb, labels, out, partials);
    final_reduce<<<1, 256, 0, stream>>>(partials, out);
}

// Round 6
// 160.812 us; speedup vs baseline: 1.4522x; 1.0329x over previous
//
#include <hip/hip_runtime.h>
#include <cstdint>

// Hierarchical classification head, R6:
//   cast         : fp32 -> fp8 e4m3 X and W (W pre-scaled x16: U(-1/32,1/32)
//                  would land subnormal; x16 puts it in normal range), bias fp32
//   gemm_sig     : Zb = sigmoid((Xq @ Wq^T)/16 + b) bf16; fp8 MFMA 16x16x32,
//                  BK=128 (4 x 32-wide panels, 32 KB LDS total, 8 barrier-iters
//                  vs 16 in R5); XCD band swizzle kept (R4: FETCH 85->34 MB).
//   logits_loss  : per-row logits3 -> d_out (float4), CE partial (no atomic:
//                  single-address atomicAdd measured +35-40 us in R2/R4)
//   final_reduce : 4096 partials -> mean loss scalar

typedef unsigned short u16;
typedef unsigned char u8;
typedef long i64;
typedef float f32x4 __attribute__((ext_vector_type(4)));

#define AS_G __attribute__((address_space(1)))
#define AS_L __attribute__((address_space(3)))

constexpr int BATCH = 4096;
constexpr int H     = 1024;
constexpr int N1 = 28, N2 = 280, N3 = 2800;
constexpr int NT = N1 + N2 + N3;   // 3108
constexpr int NP = 3200;           // 25 * 128
constexpr float WSCALE = 16.0f;
constexpr float WINV   = 1.0f / 16.0f;

__device__ inline u16 f2bf(float f) {
    unsigned int u = __float_as_uint(f);
    u += 0x7fffu + ((u >> 16) & 1u);
    return (u16)(u >> 16);
}
__device__ inline float bf2f(unsigned int u) { return __uint_as_float(u << 16); }

// pack 4 fp32 -> 4 fp8 e4m3 bytes
__device__ inline unsigned int pk4_fp8(float a, float b, float c, float d) {
    unsigned int r = __builtin_amdgcn_cvt_pk_fp8_f32(a, b, 0, false);       // bytes 0,1
    r = __builtin_amdgcn_cvt_pk_fp8_f32(c, d, (int)r, true);                // bytes 2,3
    return r;
}

// ---------------- cast fp32 -> fp8 + fused bias ----------------
constexpr int XG = (BATCH * H) / 4;   // 1,048,576 groups of 4
constexpr int WG = (NP * H) / 4;      //   819,200
constexpr int BG = NP / 4;            //       800

__global__ __launch_bounds__(256) void cast_kernel(
        const float* __restrict__ x,
        const float* __restrict__ W1, const float* __restrict__ W2,
        const float* __restrict__ W3,
        const float* __restrict__ b1, const float* __restrict__ b2,
        const float* __restrict__ b3,
        u8* __restrict__ Xq, u8* __restrict__ Wq, float* __restrict__ biasf) {
    int g = blockIdx.x * 256 + threadIdx.x;
    if (g < XG) {
        float4 v = ((const float4*)x)[g];
        ((unsigned int*)Xq)[g] = pk4_fp8(v.x, v.y, v.z, v.w);
    } else if (g < XG + WG) {
        int wg = g - XG;
        int row = wg >> 8, cg = wg & 255;
        float4 v = make_float4(0.f, 0.f, 0.f, 0.f);
        if (row < N1)           v = ((const float4*)W1)[row * 256 + cg];
        else if (row < N1 + N2) v = ((const float4*)W2)[(row - N1) * 256 + cg];
        else if (row < NT)      v = ((const float4*)W3)[(row - N1 - N2) * 256 + cg];
        ((unsigned int*)Wq)[wg] = pk4_fp8(v.x * WSCALE, v.y * WSCALE, v.z * WSCALE, v.w * WSCALE);
    } else if (g < XG + WG + BG) {
        int bg = g - XG - WG;
        float4 v; float* vp = &v.x;
        #pragma unroll
        for (int i = 0; i < 4; ++i) {
            int c = bg * 4 + i; float t = 0.f;
            if (c < N1)           t = b1[c];
            else if (c < N1 + N2) t = b2[c - N1];
            else if (c < NT)      t = b3[c - N1 - N2];
            vp[i] = t;
        }
        ((float4*)biasf)[bg] = v;
    }
}

// ---------------- GEMM: Zb = sigmoid(acc/16 + bias), fp8 inputs, bf16 out ----------------
// 128x128 tile, BK=128 as four 32-wide fp8 panels, 4 waves 2x2, 8 barrier-iters.
__global__ __launch_bounds__(256) void gemm_sig(
        const u8* __restrict__ Xq, const u8* __restrict__ Wq,
        const float* __restrict__ biasf, u16* __restrict__ Zb) {
    // [4 panels][128 rows][32 fp8] = 16 KB per matrix
    __shared__ __align__(16) u8 As[4 * 128 * 32];
    __shared__ __align__(16) u8 Bs[4 * 128 * 32];

    // XCD band swizzle (R4: FETCH 85->34 MB)
    const int id  = blockIdx.x;        // 0..799
    const int xcd = id & 7;
    const int j   = id >> 3;           // 0..99
    const int m0 = ((xcd << 2) | (j & 3)) * 128;   // m-tile 0..31
    const int n0 = (j >> 2) * 128;                 // n-tile 0..24

    const int tid  = threadIdx.x;
    const int lane = tid & 63;
    const int wave = tid >> 6;
    const int wr = wave >> 1;
    const int wc = wave & 1;

    const int laneM = lane & 15;
    const int laneKb = (lane >> 4) * 8;    // byte offset of 8-fp8 fragment in 32B row

    // staging: 1024 chunks of 16B per matrix per iter; thread does chunks
    // tid+256t, t=0..3. chunk c: panel=c>>8, rem=c&255, row=rem>>1, half=rem&1.
    // LDS byte = 16*c (linear, lane-contiguous); global byte = row*H + panel*32 + half*16.
    int crow[4], cgoff[4];
    #pragma unroll
    for (int t = 0; t < 4; ++t) {
        const int c = tid + 256 * t;
        const int panel = c >> 8, rem = c & 255;
        crow[t]  = rem >> 1;
        cgoff[t] = panel * 32 + (rem & 1) * 16;
    }

    f32x4 acc[4][4] = {};

    for (int kt = 0; kt < H / 128; ++kt) {          // 8 iterations
        const int k0 = kt * 128;
        #pragma unroll
        for (int t = 0; t < 4; ++t) {
            const int c = tid + 256 * t;
            __builtin_amdgcn_global_load_lds(
                (const AS_G uint32_t*)(Xq + (size_t)(m0 + crow[t]) * H + k0 + cgoff[t]),
                (AS_L uint32_t*)&As[c * 16], 16, 0, 0);
            __builtin_amdgcn_global_load_lds(
                (const AS_G uint32_t*)(Wq + (size_t)(n0 + crow[t]) * H + k0 + cgoff[t]),
                (AS_L uint32_t*)&Bs[c * 16], 16, 0, 0);
        }
        __syncthreads();

        #pragma unroll
        for (int p = 0; p < 4; ++p) {               // 4 k-panels of 32
            i64 af[4], bfv[4];
            #pragma unroll
            for (int i = 0; i < 4; ++i) {
                af[i]  = *(const i64*)&As[p * 4096 + (wr * 64 + i * 16 + laneM) * 32 + laneKb];
                bfv[i] = *(const i64*)&Bs[p * 4096 + (wc * 64 + i * 16 + laneM) * 32 + laneKb];
            }
            #pragma unroll
            for (int am = 0; am < 4; ++am)
                #pragma unroll
                for (int bn = 0; bn < 4; ++bn)
                    acc[am][bn] = __builtin_amdgcn_mfma_f32_16x16x32_fp8_fp8(
                        af[am], bfv[bn], acc[am][bn], 0, 0, 0);
        }
        __syncthreads();
    }

    // epilogue: C/D layout col = lane&15, row = (lane>>4)*4 + r; unscale, bf16 store
    #pragma unroll
    for (int bn = 0; bn < 4; ++bn) {
        const int col = n0 + wc * 64 + bn * 16 + laneM;
        if (col >= NT) continue;
        const float bias = biasf[col];
        #pragma unroll
        for (int am = 0; am < 4; ++am) {
            const int rbase = m0 + wr * 64 + am * 16 + (lane >> 4) * 4;
            #pragma unroll
            for (int r = 0; r < 4; ++r) {
                float v = acc[am][bn][r] * WINV + bias;
                Zb[(size_t)(rbase + r) * NP + col] = f2bf(1.0f / (1.0f + __expf(-v)));
            }
        }
    }
}

// ---------------- per-row logits + CE partial (no atomic) ----------------
__global__ __launch_bounds__(256) void logits_loss(
        const u16* __restrict__ Zb, const int* __restrict__ labels,
        float* __restrict__ out, float* __restrict__ partials) {
    __shared__ float zs[NT];               // z1 | z2 | z3
    __shared__ float red[12];
    const int b = blockIdx.x, tid = threadIdx.x;

    const unsigned int* Zr = (const unsigned int*)(Zb + (size_t)b * NP);
    for (int i = tid; i < NT / 2; i += 256) {
        unsigned int v = Zr[i];
        zs[2 * i]     = bf2f(v & 0xffffu);
        zs[2 * i + 1] = bf2f(v >> 16);
    }
    __syncthreads();

    const float* z1s = zs;
    const float* z2s = zs + N1;
    const float* z3s = zs + N1 + N2;

    float se1 = 0.f, se2 = 0.f, se3 = 0.f;
    float4* outr4 = (float4*)(out + (size_t)b * N3);
    for (int q = tid; q < N3 / 4; q += 256) {
        const int k = q * 4;
        float4 o; float* op = &o.x;
        #pragma unroll
        for (int u = 0; u < 4; ++u) {
            const int kk = k + u;
            float lg = z3s[kk] * z3s[kk / 10] * z3s[kk / 100];
            op[u] = lg;
            se3 += __expf(lg);
        }
        outr4[q] = o;
    }
    for (int jj = tid; jj < N2; jj += 256)
        se2 += __expf(z2s[jj] * z2s[jj / 10]);
    if (tid < N1)
        se1 = __expf(z1s[tid]);

    #pragma unroll
    for (int off = 32; off > 0; off >>= 1) {
        se1 += __shfl_down(se1, off, 64);
        se2 += __shfl_down(se2, off, 64);
        se3 += __shfl_down(se3, off, 64);
    }
    if ((tid & 63) == 0) {
        int w = tid >> 6;
        red[w] = se3; red[4 + w] = se2; red[8 + w] = se1;
    }
    __syncthreads();
    if (tid == 0) {
        float s3 = red[0] + red[1] + red[2] + red[3];
        float s2 = red[4] + red[5] + red[6] + red[7];
        float s1 = red[8] + red[9] + red[10] + red[11];
        int lab  = labels[b];
        int lab2 = lab / 10, lab1 = lab / 100;
        float l1 = z1s[lab1];
        float l2 = z2s[lab2] * z2s[lab2 / 10];
        float l3 = z3s[lab] * z3s[lab2] * z3s[lab1];
        partials[b] = (logf(s1) - l1) + (logf(s2) - l2) + (logf(s3) - l3);
    }
}

// ---------------- final loss reduce ----------------
__global__ __launch_bounds__(256) void final_reduce(
        const float* __restrict__ partials, float* __restrict__ out) {
    __shared__ float red[4];
    const int tid = threadIdx.x;
    float s = 0.f;
    for (int i = tid; i < BATCH; i += 256) s += partials[i];
    #pragma unroll
    for (int off = 32; off > 0; off >>= 1) s += __shfl_down(s, off, 64);
    if ((tid & 63) == 0) red[tid >> 6] = s;
    __syncthreads();
    if (tid == 0)
        out[(size_t)BATCH * N3] = (red[0] + red[1] + red[2] + red[3]) * (1.0f / BATCH);
}

extern "C" void kernel_launch(void* const* d_in, const int* in_sizes, int n_in,
                              void* d_out, int out_size, void* d_ws, size_t ws_size,
                              hipStream_t stream) {
    const float* x      = (const float*)d_in[0];
    const int*   labels = (const int*)d_in[1];
    const float* W1     = (const float*)d_in[2];
    const float* b1     = (const float*)d_in[3];
    const float* W2     = (const float*)d_in[4];
    const float* b2     = (const float*)d_in[5];
    const float* W3     = (const float*)d_in[6];
    const float* b3     = (const float*)d_in[7];
    float* out = (float*)d_out;

    char* ws = (char*)d_ws;
    u8*    Xq       = (u8*)ws;                     //  4,194,304 B  [4096][1024] fp8
    u8*    Wq       = (u8*)(ws + 4194304);         //  3,276,800 B  [3200][1024] fp8
    u16*   Zb       = (u16*)(ws + 7471104);        // 26,214,400 B  [4096][3200] bf16
    float* biasf    = (float*)(ws + 33685504);     //     12,800 B
    float* partials = (float*)(ws + 33698304);     //     16,384 B
    // total ws use: 33,714,688 B

    cast_kernel<<<(XG + WG + BG + 255) / 256, 256, 0, stream>>>(
        x, W1, W2, W3, b1, b2, b3, Xq, Wq, biasf);
    gemm_sig<<<800, 256, 0, stream>>>(Xq, Wq, biasf, Zb);
    logits_loss<<<BATCH, 256, 0, stream>>>(Zb, labels, out, partials);
    final_reduce<<<1, 256, 0, stream>>>(partials, out);
}

// Round 7
// 153.119 us; speedup vs baseline: 1.5251x; 1.0502x over previous
//
#include <hip/hip_runtime.h>
#include <cstdint>

// Hierarchical classification head, R7:
//   cast         : fp32 -> fp8 e4m3 X and W (W pre-scaled x16), bias fp32
//   gemm_sig     : Zb = sigmoid((Xq @ Wq^T)/16 + b) bf16; fp8 MFMA 16x16x32,
//                  BK=128, 8 barrier-iters; XCD band swizzle (R4);
//                  NEW: 16B-rotation LDS swizzle keyed on row bit2 kills the
//                  4-way ds_read_b64 bank conflict (R6: 9.83M cycles == exactly
//                  12 extra cyc x 819k reads; this layout gives 2-way = free).
//   logits_loss  : per-row logits3 -> d_out (float4), CE partial (no atomic)
//   final_reduce : 4096 partials -> mean loss scalar

typedef unsigned short u16;
typedef unsigned char u8;
typedef long i64;
typedef float f32x4 __attribute__((ext_vector_type(4)));

#define AS_G __attribute__((address_space(1)))
#define AS_L __attribute__((address_space(3)))

constexpr int BATCH = 4096;
constexpr int H     = 1024;
constexpr int N1 = 28, N2 = 280, N3 = 2800;
constexpr int NT = N1 + N2 + N3;   // 3108
constexpr int NP = 3200;           // 25 * 128
constexpr float WSCALE = 16.0f;
constexpr float WINV   = 1.0f / 16.0f;

__device__ inline u16 f2bf(float f) {
    unsigned int u = __float_as_uint(f);
    u += 0x7fffu + ((u >> 16) & 1u);
    return (u16)(u >> 16);
}
__device__ inline float bf2f(unsigned int u) { return __uint_as_float(u << 16); }

__device__ inline unsigned int pk4_fp8(float a, float b, float c, float d) {
    unsigned int r = __builtin_amdgcn_cvt_pk_fp8_f32(a, b, 0, false);
    r = __builtin_amdgcn_cvt_pk_fp8_f32(c, d, (int)r, true);
    return r;
}

// ---------------- cast fp32 -> fp8 + fused bias ----------------
constexpr int XG = (BATCH * H) / 4;   // 1,048,576
constexpr int WG = (NP * H) / 4;      //   819,200
constexpr int BG = NP / 4;            //       800

__global__ __launch_bounds__(256) void cast_kernel(
        const float* __restrict__ x,
        const float* __restrict__ W1, const float* __restrict__ W2,
        const float* __restrict__ W3,
        const float* __restrict__ b1, const float* __restrict__ b2,
        const float* __restrict__ b3,
        u8* __restrict__ Xq, u8* __restrict__ Wq, float* __restrict__ biasf) {
    int g = blockIdx.x * 256 + threadIdx.x;
    if (g < XG) {
        float4 v = ((const float4*)x)[g];
        ((unsigned int*)Xq)[g] = pk4_fp8(v.x, v.y, v.z, v.w);
    } else if (g < XG + WG) {
        int wg = g - XG;
        int row = wg >> 8, cg = wg & 255;
        float4 v = make_float4(0.f, 0.f, 0.f, 0.f);
        if (row < N1)           v = ((const float4*)W1)[row * 256 + cg];
        else if (row < N1 + N2) v = ((const float4*)W2)[(row - N1) * 256 + cg];
        else if (row < NT)      v = ((const float4*)W3)[(row - N1 - N2) * 256 + cg];
        ((unsigned int*)Wq)[wg] = pk4_fp8(v.x * WSCALE, v.y * WSCALE, v.z * WSCALE, v.w * WSCALE);
    } else if (g < XG + WG + BG) {
        int bg = g - XG - WG;
        float4 v; float* vp = &v.x;
        #pragma unroll
        for (int i = 0; i < 4; ++i) {
            int c = bg * 4 + i; float t = 0.f;
            if (c < N1)           t = b1[c];
            else if (c < N1 + N2) t = b2[c - N1];
            else if (c < NT)      t = b3[c - N1 - N2];
            vp[i] = t;
        }
        ((float4*)biasf)[bg] = v;
    }
}

// ---------------- GEMM: Zb = sigmoid(acc/16 + bias), fp8 inputs, bf16 out ----------------
// 128x128 tile, BK=128 (4 x 32B fp8 panels), 4 waves 2x2, 8 barrier-iters.
// LDS layout: within each 32B row, the two 16B units are swapped when
// (row>>2)&1 == 1. Staging permutes the GLOBAL offset (LDS stays lane-linear,
// as global_load_lds requires); fragment reads fold the XOR into a per-lane
// constant. Result: quarter-phase bank multiplicity 4 -> 2 (free).
__global__ __launch_bounds__(256) void gemm_sig(
        const u8* __restrict__ Xq, const u8* __restrict__ Wq,
        const float* __restrict__ biasf, u16* __restrict__ Zb) {
    __shared__ __align__(16) u8 As[4 * 128 * 32];
    __shared__ __align__(16) u8 Bs[4 * 128 * 32];

    // XCD band swizzle (R4: FETCH 85->34 MB)
    const int id  = blockIdx.x;        // 0..799
    const int xcd = id & 7;
    const int j   = id >> 3;           // 0..99
    const int m0 = ((xcd << 2) | (j & 3)) * 128;   // m-tile 0..31
    const int n0 = (j >> 2) * 128;                 // n-tile 0..24

    const int tid  = threadIdx.x;
    const int lane = tid & 63;
    const int wave = tid >> 6;
    const int wr = wave >> 1;
    const int wc = wave & 1;

    const int laneM = lane & 15;
    // swizzled fragment offset: u = lane>>4 selects the 8B unit; 16B unit index
    // is (u>>1) ^ ((row>>2)&1); row bit2 parity == (laneM>>2)&1 for all frags.
    const int u   = lane >> 4;
    const int xb  = (laneM >> 2) & 1;
    const int laneKb = (((u >> 1) ^ xb) << 4) + (u & 1) * 8;

    // staging: chunk c (16B): panel=c>>8, rem=c&255, row=rem>>1, v=rem&1.
    // LDS byte = 16*c (linear). Global 16B unit = v ^ ((row>>2)&1).
    int crow[4], cgoff[4];
    #pragma unroll
    for (int t = 0; t < 4; ++t) {
        const int c = tid + 256 * t;
        const int panel = c >> 8, rem = c & 255;
        const int row = rem >> 1, v = rem & 1;
        crow[t]  = row;
        cgoff[t] = panel * 32 + ((v ^ ((row >> 2) & 1)) << 4);
    }

    f32x4 acc[4][4] = {};

    for (int kt = 0; kt < H / 128; ++kt) {          // 8 iterations
        const int k0 = kt * 128;
        #pragma unroll
        for (int t = 0; t < 4; ++t) {
            const int c = tid + 256 * t;
            __builtin_amdgcn_global_load_lds(
                (const AS_G uint32_t*)(Xq + (size_t)(m0 + crow[t]) * H + k0 + cgoff[t]),
                (AS_L uint32_t*)&As[c * 16], 16, 0, 0);
            __builtin_amdgcn_global_load_lds(
                (const AS_G uint32_t*)(Wq + (size_t)(n0 + crow[t]) * H + k0 + cgoff[t]),
                (AS_L uint32_t*)&Bs[c * 16], 16, 0, 0);
        }
        __syncthreads();

        #pragma unroll
        for (int p = 0; p < 4; ++p) {               // 4 k-panels of 32
            i64 af[4], bfv[4];
            #pragma unroll
            for (int i = 0; i < 4; ++i) {
                af[i]  = *(const i64*)&As[p * 4096 + (wr * 64 + i * 16 + laneM) * 32 + laneKb];
                bfv[i] = *(const i64*)&Bs[p * 4096 + (wc * 64 + i * 16 + laneM) * 32 + laneKb];
            }
            #pragma unroll
            for (int am = 0; am < 4; ++am)
                #pragma unroll
                for (int bn = 0; bn < 4; ++bn)
                    acc[am][bn] = __builtin_amdgcn_mfma_f32_16x16x32_fp8_fp8(
                        af[am], bfv[bn], acc[am][bn], 0, 0, 0);
        }
        __syncthreads();
    }

    // epilogue: C/D layout col = lane&15, row = (lane>>4)*4 + r; unscale, bf16 store
    #pragma unroll
    for (int bn = 0; bn < 4; ++bn) {
        const int col = n0 + wc * 64 + bn * 16 + laneM;
        if (col >= NT) continue;
        const float bias = biasf[col];
        #pragma unroll
        for (int am = 0; am < 4; ++am) {
            const int rbase = m0 + wr * 64 + am * 16 + (lane >> 4) * 4;
            #pragma unroll
            for (int r = 0; r < 4; ++r) {
                float v = acc[am][bn][r] * WINV + bias;
                Zb[(size_t)(rbase + r) * NP + col] = f2bf(1.0f / (1.0f + __expf(-v)));
            }
        }
    }
}

// ---------------- per-row logits + CE partial (no atomic) ----------------
__global__ __launch_bounds__(256) void logits_loss(
        const u16* __restrict__ Zb, const int* __restrict__ labels,
        float* __restrict__ out, float* __restrict__ partials) {
    __shared__ float zs[NT];               // z1 | z2 | z3
    __shared__ float red[12];
    const int b = blockIdx.x, tid = threadIdx.x;

    const unsigned int* Zr = (const unsigned int*)(Zb + (size_t)b * NP);
    for (int i = tid; i < NT / 2; i += 256) {
        unsigned int v = Zr[i];
        zs[2 * i]     = bf2f(v & 0xffffu);
        zs[2 * i + 1] = bf2f(v >> 16);
    }
    __syncthreads();

    const float* z1s = zs;
    const float* z2s = zs + N1;
    const float* z3s = zs + N1 + N2;

    float se1 = 0.f, se2 = 0.f, se3 = 0.f;
    float4* outr4 = (float4*)(out + (size_t)b * N3);
    for (int q = tid; q < N3 / 4; q += 256) {
        const int k = q * 4;
        float4 o; float* op = &o.x;
        #pragma unroll
        for (int uu = 0; uu < 4; ++uu) {
            const int kk = k + uu;
            float lg = z3s[kk] * z3s[kk / 10] * z3s[kk / 100];
            op[uu] = lg;
            se3 += __expf(lg);
        }
        outr4[q] = o;
    }
    for (int jj = tid; jj < N2; jj += 256)
        se2 += __expf(z2s[jj] * z2s[jj / 10]);
    if (tid < N1)
        se1 = __expf(z1s[tid]);

    #pragma unroll
    for (int off = 32; off > 0; off >>= 1) {
        se1 += __shfl_down(se1, off, 64);
        se2 += __shfl_down(se2, off, 64);
        se3 += __shfl_down(se3, off, 64);
    }
    if ((tid & 63) == 0) {
        int w = tid >> 6;
        red[w] = se3; red[4 + w] = se2; red[8 + w] = se1;
    }
    __syncthreads();
    if (tid == 0) {
        float s3 = red[0] + red[1] + red[2] + red[3];
        float s2 = red[4] + red[5] + red[6] + red[7];
        float s1 = red[8] + red[9] + red[10] + red[11];
        int lab  = labels[b];
        int lab2 = lab / 10, lab1 = lab / 100;
        float l1 = z1s[lab1];
        float l2 = z2s[lab2] * z2s[lab2 / 10];
        float l3 = z3s[lab] * z3s[lab2] * z3s[lab1];
        partials[b] = (logf(s1) - l1) + (logf(s2) - l2) + (logf(s3) - l3);
    }
}

// ---------------- final loss reduce ----------------
__global__ __launch_bounds__(256) void final_reduce(
        const float* __restrict__ partials, float* __restrict__ out) {
    __shared__ float red[4];
    const int tid = threadIdx.x;
    float s = 0.f;
    for (int i = tid; i < BATCH; i += 256) s += partials[i];
    #pragma unroll
    for (int off = 32; off > 0; off >>= 1) s += __shfl_down(s, off, 64);
    if ((tid & 63) == 0) red[tid >> 6] = s;
    __syncthreads();
    if (tid == 0)
        out[(size_t)BATCH * N3] = (red[0] + red[1] + red[2] + red[3]) * (1.0f / BATCH);
}

extern "C" void kernel_launch(void* const* d_in, const int* in_sizes, int n_in,
                              void* d_out, int out_size, void* d_ws, size_t ws_size,
                              hipStream_t stream) {
    const float* x      = (const float*)d_in[0];
    const int*   labels = (const int*)d_in[1];
    const float* W1     = (const float*)d_in[2];
    const float* b1     = (const float*)d_in[3];
    const float* W2     = (const float*)d_in[4];
    const float* b2     = (const float*)d_in[5];
    const float* W3     = (const float*)d_in[6];
    const float* b3     = (const float*)d_in[7];
    float* out = (float*)d_out;

    char* ws = (char*)d_ws;
    u8*    Xq       = (u8*)ws;                     //  4,194,304 B  [4096][1024] fp8
    u8*    Wq       = (u8*)(ws + 4194304);         //  3,276,800 B  [3200][1024] fp8
    u16*   Zb       = (u16*)(ws + 7471104);        // 26,214,400 B  [4096][3200] bf16
    float* biasf    = (float*)(ws + 33685504);     //     12,800 B
    float* partials = (float*)(ws + 33698304);     //     16,384 B
    // total ws use: 33,714,688 B

    cast_kernel<<<(XG + WG + BG + 255) / 256, 256, 0, stream>>>(
        x, W1, W2, W3, b1, b2, b3, Xq, Wq, biasf);
    gemm_sig<<<800, 256, 0, stream>>>(Xq, Wq, biasf, Zb);
    logits_loss<<<BATCH, 256, 0, stream>>>(Zb, labels, out, partials);
    final_reduce<<<1, 256, 0, stream>>>(partials, out);
}

// Round 8
// 146.170 us; speedup vs baseline: 1.5976x; 1.0475x over previous
//
#include <hip/hip_runtime.h>
#include <cstdint>

// Hierarchical classification head, R8:
//   cast         : fp32 -> fp8 e4m3 X and W (W pre-scaled x16), bias fp32
//   gemm_sig     : Zb = sigmoid((Xq @ Wq^T)/16 + b) bf16; fp8 MFMA 16x16x32,
//                  BK=128, 8 barrier-iters; 16B-rotation LDS swizzle (R7:
//                  conflicts 9.8M->3.3M, -6 us); XCD band swizzle (R4).
//                  NEW: 64x128 tile -> 1600 blocks = 6.25/CU (R7 was 800 =
//                  3.1/CU, OccupancyPercent 15% and 53% idle: grid-limited).
//   logits_loss  : per-row logits3 -> d_out; ONLY 588 ancestor z in LDS,
//                  z3[k] streamed from global (kills the 2800-elem LDS pass)
//   final_reduce : 4096 partials -> mean loss scalar

typedef unsigned short u16;
typedef unsigned char u8;
typedef long i64;
typedef float f32x4 __attribute__((ext_vector_type(4)));

#define AS_G __attribute__((address_space(1)))
#define AS_L __attribute__((address_space(3)))

constexpr int BATCH = 4096;
constexpr int H     = 1024;
constexpr int N1 = 28, N2 = 280, N3 = 2800;
constexpr int NT = N1 + N2 + N3;   // 3108
constexpr int NP = 3200;           // 25 * 128
constexpr int NANC = N1 + N2 + 280;  // 588 ancestor values
constexpr float WSCALE = 16.0f;
constexpr float WINV   = 1.0f / 16.0f;

__device__ inline u16 f2bf(float f) {
    unsigned int u = __float_as_uint(f);
    u += 0x7fffu + ((u >> 16) & 1u);
    return (u16)(u >> 16);
}
__device__ inline float bf2f(unsigned int u) { return __uint_as_float(u << 16); }

__device__ inline unsigned int pk4_fp8(float a, float b, float c, float d) {
    unsigned int r = __builtin_amdgcn_cvt_pk_fp8_f32(a, b, 0, false);
    r = __builtin_amdgcn_cvt_pk_fp8_f32(c, d, (int)r, true);
    return r;
}

// ---------------- cast fp32 -> fp8 + fused bias ----------------
constexpr int XG = (BATCH * H) / 4;   // 1,048,576
constexpr int WG = (NP * H) / 4;      //   819,200
constexpr int BG = NP / 4;            //       800

__global__ __launch_bounds__(256) void cast_kernel(
        const float* __restrict__ x,
        const float* __restrict__ W1, const float* __restrict__ W2,
        const float* __restrict__ W3,
        const float* __restrict__ b1, const float* __restrict__ b2,
        const float* __restrict__ b3,
        u8* __restrict__ Xq, u8* __restrict__ Wq, float* __restrict__ biasf) {
    int g = blockIdx.x * 256 + threadIdx.x;
    if (g < XG) {
        float4 v = ((const float4*)x)[g];
        ((unsigned int*)Xq)[g] = pk4_fp8(v.x, v.y, v.z, v.w);
    } else if (g < XG + WG) {
        int wg = g - XG;
        int row = wg >> 8, cg = wg & 255;
        float4 v = make_float4(0.f, 0.f, 0.f, 0.f);
        if (row < N1)           v = ((const float4*)W1)[row * 256 + cg];
        else if (row < N1 + N2) v = ((const float4*)W2)[(row - N1) * 256 + cg];
        else if (row < NT)      v = ((const float4*)W3)[(row - N1 - N2) * 256 + cg];
        ((unsigned int*)Wq)[wg] = pk4_fp8(v.x * WSCALE, v.y * WSCALE, v.z * WSCALE, v.w * WSCALE);
    } else if (g < XG + WG + BG) {
        int bg = g - XG - WG;
        float4 v; float* vp = &v.x;
        #pragma unroll
        for (int i = 0; i < 4; ++i) {
            int c = bg * 4 + i; float t = 0.f;
            if (c < N1)           t = b1[c];
            else if (c < N1 + N2) t = b2[c - N1];
            else if (c < NT)      t = b3[c - N1 - N2];
            vp[i] = t;
        }
        ((float4*)biasf)[bg] = v;
    }
}

// ---------------- GEMM: Zb = sigmoid(acc/16 + bias), fp8 inputs, bf16 out ----------------
// 64x128 tile, BK=128 (4 x 32B panels), 4 waves 2x2 (wave = 32 rows x 64 cols),
// 8 barrier-iters, 1600 blocks. LDS 24 KB -> 6 blocks/CU resource-fit.
__global__ __launch_bounds__(256) void gemm_sig(
        const u8* __restrict__ Xq, const u8* __restrict__ Wq,
        const float* __restrict__ biasf, u16* __restrict__ Zb) {
    __shared__ __align__(16) u8 As[4 * 64 * 32];    //  8 KB
    __shared__ __align__(16) u8 Bs[4 * 128 * 32];   // 16 KB

    // XCD band swizzle: 64 m-tiles x 25 n-tiles; XCD owns 8-m-tile band.
    // Per-XCD working set: A band 512 KB + B stream 3.2 MB < 4 MB L2.
    const int id  = blockIdx.x;        // 0..1599
    const int xcd = id & 7;
    const int j   = id >> 3;           // 0..199
    const int m0 = ((xcd << 3) | (j & 7)) * 64;    // m-tile 0..63
    const int n0 = (j >> 3) * 128;                 // n-tile 0..24

    const int tid  = threadIdx.x;
    const int lane = tid & 63;
    const int wave = tid >> 6;
    const int wr = wave >> 1;          // m half (32 rows)
    const int wc = wave & 1;           // n half (64 cols)

    const int laneM = lane & 15;
    // 16B-rotation swizzle (R7): unit index = (u>>1) ^ ((row>>2)&1)
    const int u   = lane >> 4;
    const int xb  = (laneM >> 2) & 1;
    const int laneKb = (((u >> 1) ^ xb) << 4) + (u & 1) * 8;

    // A staging: 512 chunks (16B); thread does c = tid, tid+256.
    // chunk c: panel=c>>7, rem=c&127, row=rem>>1, v=rem&1.
    int arow[2], agoff[2];
    #pragma unroll
    for (int t = 0; t < 2; ++t) {
        const int c = tid + 256 * t;
        const int panel = c >> 7, rem = c & 127;
        const int row = rem >> 1, v = rem & 1;
        arow[t]  = row;
        agoff[t] = panel * 32 + ((v ^ ((row >> 2) & 1)) << 4);
    }
    // B staging: 1024 chunks; thread does c = tid + 256t, t=0..3.
    int brow[4], bgoff[4];
    #pragma unroll
    for (int t = 0; t < 4; ++t) {
        const int c = tid + 256 * t;
        const int panel = c >> 8, rem = c & 255;
        const int row = rem >> 1, v = rem & 1;
        brow[t]  = row;
        bgoff[t] = panel * 32 + ((v ^ ((row >> 2) & 1)) << 4);
    }

    f32x4 acc[2][4] = {};

    for (int kt = 0; kt < H / 128; ++kt) {          // 8 iterations
        const int k0 = kt * 128;
        #pragma unroll
        for (int t = 0; t < 2; ++t) {
            const int c = tid + 256 * t;
            __builtin_amdgcn_global_load_lds(
                (const AS_G uint32_t*)(Xq + (size_t)(m0 + arow[t]) * H + k0 + agoff[t]),
                (AS_L uint32_t*)&As[c * 16], 16, 0, 0);
        }
        #pragma unroll
        for (int t = 0; t < 4; ++t) {
            const int c = tid + 256 * t;
            __builtin_amdgcn_global_load_lds(
                (const AS_G uint32_t*)(Wq + (size_t)(n0 + brow[t]) * H + k0 + bgoff[t]),
                (AS_L uint32_t*)&Bs[c * 16], 16, 0, 0);
        }
        __syncthreads();

        #pragma unroll
        for (int p = 0; p < 4; ++p) {               // 4 k-panels of 32
            i64 af[2], bfv[4];
            #pragma unroll
            for (int i = 0; i < 2; ++i)
                af[i]  = *(const i64*)&As[p * 2048 + (wr * 32 + i * 16 + laneM) * 32 + laneKb];
            #pragma unroll
            for (int i = 0; i < 4; ++i)
                bfv[i] = *(const i64*)&Bs[p * 4096 + (wc * 64 + i * 16 + laneM) * 32 + laneKb];
            #pragma unroll
            for (int am = 0; am < 2; ++am)
                #pragma unroll
                for (int bn = 0; bn < 4; ++bn)
                    acc[am][bn] = __builtin_amdgcn_mfma_f32_16x16x32_fp8_fp8(
                        af[am], bfv[bn], acc[am][bn], 0, 0, 0);
        }
        __syncthreads();
    }

    // epilogue: C/D layout col = lane&15, row = (lane>>4)*4 + r; unscale, bf16 store
    #pragma unroll
    for (int bn = 0; bn < 4; ++bn) {
        const int col = n0 + wc * 64 + bn * 16 + laneM;
        if (col >= NT) continue;
        const float bias = biasf[col];
        #pragma unroll
        for (int am = 0; am < 2; ++am) {
            const int rbase = m0 + wr * 32 + am * 16 + (lane >> 4) * 4;
            #pragma unroll
            for (int r = 0; r < 4; ++r) {
                float v = acc[am][bn][r] * WINV + bias;
                Zb[(size_t)(rbase + r) * NP + col] = f2bf(1.0f / (1.0f + __expf(-v)));
            }
        }
    }
}

// ---------------- per-row logits + CE partial (no atomic) ----------------
// LDS holds only the 588 ancestor z (z1|z2|z3[0:280)); z3[k] streamed global.
__global__ __launch_bounds__(256) void logits_loss(
        const u16* __restrict__ Zb, const int* __restrict__ labels,
        float* __restrict__ out, float* __restrict__ partials) {
    __shared__ float zs[NANC];             // [0,28) z1 | [28,308) z2 | [308,588) z3[0:280)
    __shared__ float red[12];
    const int b = blockIdx.x, tid = threadIdx.x;
    const u16* Zrow = Zb + (size_t)b * NP;

    const unsigned int* Zr = (const unsigned int*)Zrow;
    for (int i = tid; i < NANC / 2; i += 256) {    // 294 uints
        unsigned int v = Zr[i];
        zs[2 * i]     = bf2f(v & 0xffffu);
        zs[2 * i + 1] = bf2f(v >> 16);
    }
    __syncthreads();

    float se1 = 0.f, se2 = 0.f, se3 = 0.f;
    float4* outr4 = (float4*)(out + (size_t)b * N3);
    // z3 block starts at element 308 (uint index 154, even -> uint2-aligned)
    const uint2* Z3s = (const uint2*)(Zrow + N1 + N2);
    for (int q = tid; q < N3 / 4; q += 256) {
        const uint2 zv = Z3s[q];               // z3[4q..4q+3]
        float z3v[4] = { bf2f(zv.x & 0xffffu), bf2f(zv.x >> 16),
                         bf2f(zv.y & 0xffffu), bf2f(zv.y >> 16) };
        const int k = q * 4;
        float4 o; float* op = &o.x;
        #pragma unroll
        for (int uu = 0; uu < 4; ++uu) {
            const int kk = k + uu;
            float lg = z3v[uu] * zs[308 + kk / 10] * zs[308 + kk / 100];
            op[uu] = lg;
            se3 += __expf(lg);
        }
        outr4[q] = o;
    }
    for (int jj = tid; jj < N2; jj += 256)
        se2 += __expf(zs[N1 + jj] * zs[N1 + jj / 10]);
    if (tid < N1)
        se1 = __expf(zs[tid]);

    #pragma unroll
    for (int off = 32; off > 0; off >>= 1) {
        se1 += __shfl_down(se1, off, 64);
        se2 += __shfl_down(se2, off, 64);
        se3 += __shfl_down(se3, off, 64);
    }
    if ((tid & 63) == 0) {
        int w = tid >> 6;
        red[w] = se3; red[4 + w] = se2; red[8 + w] = se1;
    }
    __syncthreads();
    if (tid == 0) {
        float s3 = red[0] + red[1] + red[2] + red[3];
        float s2 = red[4] + red[5] + red[6] + red[7];
        float s1 = red[8] + red[9] + red[10] + red[11];
        int lab  = labels[b];
        int lab2 = lab / 10, lab1 = lab / 100;
        float l1 = zs[lab1];
        float l2 = zs[N1 + lab2] * zs[N1 + lab2 / 10];
        float l3 = bf2f((unsigned int)Zrow[N1 + N2 + lab]) * zs[308 + lab2] * zs[308 + lab1];
        partials[b] = (logf(s1) - l1) + (logf(s2) - l2) + (logf(s3) - l3);
    }
}

// ---------------- final loss reduce ----------------
__global__ __launch_bounds__(256) void final_reduce(
        const float* __restrict__ partials, float* __restrict__ out) {
    __shared__ float red[4];
    const int tid = threadIdx.x;
    float s = 0.f;
    for (int i = tid; i < BATCH; i += 256) s += partials[i];
    #pragma unroll
    for (int off = 32; off > 0; off >>= 1) s += __shfl_down(s, off, 64);
    if ((tid & 63) == 0) red[tid >> 6] = s;
    __syncthreads();
    if (tid == 0)
        out[(size_t)BATCH * N3] = (red[0] + red[1] + red[2] + red[3]) * (1.0f / BATCH);
}

extern "C" void kernel_launch(void* const* d_in, const int* in_sizes, int n_in,
                              void* d_out, int out_size, void* d_ws, size_t ws_size,
                              hipStream_t stream) {
    const float* x      = (const float*)d_in[0];
    const int*   labels = (const int*)d_in[1];
    const float* W1     = (const float*)d_in[2];
    const float* b1     = (const float*)d_in[3];
    const float* W2     = (const float*)d_in[4];
    const float* b2     = (const float*)d_in[5];
    const float* W3     = (const float*)d_in[6];
    const float* b3     = (const float*)d_in[7];
    float* out = (float*)d_out;

    char* ws = (char*)d_ws;
    u8*    Xq       = (u8*)ws;                     //  4,194,304 B  [4096][1024] fp8
    u8*    Wq       = (u8*)(ws + 4194304);         //  3,276,800 B  [3200][1024] fp8
    u16*   Zb       = (u16*)(ws + 7471104);        // 26,214,400 B  [4096][3200] bf16
    float* biasf    = (float*)(ws + 33685504);     //     12,800 B
    float* partials = (float*)(ws + 33698304);     //     16,384 B
    // total ws use: 33,714,688 B

    cast_kernel<<<(XG + WG + BG + 255) / 256, 256, 0, stream>>>(
        x, W1, W2, W3, b1, b2, b3, Xq, Wq, biasf);
    gemm_sig<<<1600, 256, 0, stream>>>(Xq, Wq, biasf, Zb);
    logits_loss<<<BATCH, 256, 0, stream>>>(Zb, labels, out, partials);
    final_reduce<<<1, 256, 0, stream>>>(partials, out);
}